// Round 19
// baseline (1878.177 us; speedup 1.0000x reference)
//
#include <hip/hip_runtime.h>

// ---------------- problem constants ----------------
#define B_   2
#define T_   4096
#define D_   2048
#define HV_  32
#define AK_  128
#define UV_  128
#define KD_  2048          // KEY_DIM
#define VD_  4096          // VALUE_DIM
#define CD_  8192          // CONV_DIM
#define CHK  64            // chunk size
#define NCH  (T_/CHK)      // 64 chunks

typedef __attribute__((ext_vector_type(4))) float  f32x4;
typedef __attribute__((ext_vector_type(8))) short  short8;
typedef __attribute__((ext_vector_type(4))) short  short4b;
typedef __attribute__((ext_vector_type(8))) unsigned short u16x8;
typedef __attribute__((ext_vector_type(4))) unsigned short u16x4;

__device__ __forceinline__ float bf2f(unsigned short u) {
  return __uint_as_float(((unsigned)u) << 16);
}
__device__ __forceinline__ unsigned short f2bf(float f) { // RNE
  unsigned u = __float_as_uint(f);
  return (unsigned short)((u + 0x7fffu + ((u >> 16) & 1u)) >> 16);
}
__device__ __forceinline__ void gload16(const void* g, void* l) {
  __builtin_amdgcn_global_load_lds((const __attribute__((address_space(1))) void*)g,
                                   (__attribute__((address_space(3))) void*)l, 16, 0, 0);
}

// ---------------- transpose f32 (K,N) -> bf16 (N,K) ----------------
__global__ __launch_bounds__(256) void k_transpose(const float* __restrict__ src,
                                                   unsigned short* __restrict__ dst,
                                                   int K, int N) {
  __shared__ float tile[32][33];
  int k0 = blockIdx.x * 32, n0 = blockIdx.y * 32;
  int tx = threadIdx.x, ty = threadIdx.y;
  #pragma unroll
  for (int i = 0; i < 32; i += 8)
    tile[ty + i][tx] = src[(size_t)(k0 + ty + i) * N + n0 + tx];
  __syncthreads();
  #pragma unroll
  for (int i = 0; i < 32; i += 8)
    dst[(size_t)(n0 + ty + i) * K + k0 + tx] = f2bf(tile[tx][ty + i]);
}

// ---------------- transpose f32 (K,N) -> f32 (N,K) (for W_b/W_a) ----------------
__global__ __launch_bounds__(256) void k_transpose_f32(const float* __restrict__ src,
                                                       float* __restrict__ dst,
                                                       int K, int N) {
  __shared__ float tile[32][33];
  int k0 = blockIdx.x * 32, n0 = blockIdx.y * 32;
  int tx = threadIdx.x, ty = threadIdx.y;
  #pragma unroll
  for (int i = 0; i < 32; i += 8)
    tile[ty + i][tx] = src[(size_t)(k0 + ty + i) * N + n0 + tx];
  __syncthreads();
  #pragma unroll
  for (int i = 0; i < 32; i += 8)
    dst[(size_t)(n0 + ty + i) * K + k0 + tx] = tile[tx][ty + i];
}

// ---------------- MFMA GEMM, 128x256 tile, BK=64, band/XCD-swizzled (r15-proven) ----------------
__device__ __forceinline__ void storeC(float* p, float v) { *p = v; }
__device__ __forceinline__ void storeC(unsigned short* p, float v) { *p = f2bf(v); }

template <bool AGL, typename CT>
__global__ __launch_bounds__(256, 2) void k_gemm(const void* __restrict__ Av,
                                                 const unsigned short* __restrict__ BT,
                                                 CT* __restrict__ C, int N, int K) {
  __shared__ __attribute__((aligned(16))) short As[128 * 64];
  __shared__ __attribute__((aligned(16))) short Bs[256 * 64];
  const int tid  = threadIdx.x;
  const int bid  = blockIdx.x;
  const int tb   = bid & 63;
  const size_t bm = (size_t)(8 * (tb & 7) + (tb >> 3)) * 128;
  const size_t bn = (size_t)(bid >> 6) * 256;
  const int lane = tid & 63;
  const int wave = tid >> 6;
  const int wm = (wave >> 1) * 64;
  const int wn = (wave & 1) * 64;
  const int fr = lane & 15;
  const int kg = lane >> 4;
  const int lr = lane >> 3, lc8 = (lane & 7) * 8;
  const short* gb = (const short*)BT + (bn + wave * 64 + lr) * (size_t)K + lc8;
  short* lB = &Bs[wave * 64 * 64];
  const short* gab = (const short*)Av + (bm + wave * 32 + lr) * (size_t)K + lc8; // AGL path
  short* lA = &As[wave * 32 * 64];

  f32x4 acc[4][8];
  #pragma unroll
  for (int i = 0; i < 4; ++i)
    #pragma unroll
    for (int j2 = 0; j2 < 8; ++j2) acc[i][j2] = (f32x4){0.f, 0.f, 0.f, 0.f};

  for (int kt = 0; kt < K; kt += 64) {
    __syncthreads();
    #pragma unroll
    for (int p = 0; p < 8; ++p)
      gload16(gb + kt + (size_t)(8 * p) * K, lB + (8 * p) * 64);
    if constexpr (AGL) {
      #pragma unroll
      for (int p = 0; p < 4; ++p)
        gload16(gab + kt + (size_t)(8 * p) * K, lA + (8 * p) * 64);
    } else {
      const float* Ag = (const float*)Av + bm * (size_t)K;
      #pragma unroll
      for (int s = 0; s < 8; ++s) {
        int ch = s * 256 + tid;
        int r = ch >> 4, c4 = (ch & 15) * 4;
        float4 v = *(const float4*)(Ag + (size_t)r * K + kt + c4);
        short4b sv = { (short)f2bf(v.x), (short)f2bf(v.y), (short)f2bf(v.z), (short)f2bf(v.w) };
        *(short4b*)&As[r * 64 + c4] = sv;
      }
    }
    __syncthreads();
    #pragma unroll
    for (int kk = 0; kk < 2; ++kk) {
      short8 af[4], bfr[8];
      #pragma unroll
      for (int mi = 0; mi < 4; ++mi) af[mi] = *(const short8*)&As[(wm + mi*16 + fr)*64 + kk*32 + kg*8];
      #pragma unroll
      for (int ni = 0; ni < 4; ++ni) {
        bfr[ni]     = *(const short8*)&Bs[(wn + ni*16 + fr)*64 + kk*32 + kg*8];
        bfr[4 + ni] = *(const short8*)&Bs[(128 + wn + ni*16 + fr)*64 + kk*32 + kg*8];
      }
      #pragma unroll
      for (int mi = 0; mi < 4; ++mi)
        #pragma unroll
        for (int ni = 0; ni < 8; ++ni)
          acc[mi][ni] = __builtin_amdgcn_mfma_f32_16x16x32_bf16(af[mi], bfr[ni], acc[mi][ni], 0, 0, 0);
    }
  }
  #pragma unroll
  for (int mi = 0; mi < 4; ++mi)
    #pragma unroll
    for (int ni = 0; ni < 8; ++ni) {
      size_t row = bm + wm + mi * 16 + kg * 4;
      size_t col = bn + (ni >= 4 ? 128 : 0) + wn + (ni & 3) * 16 + fr;
      #pragma unroll
      for (int e = 0; e < 4; ++e) storeC(&C[(row + e) * (size_t)N + col], acc[mi][ni][e]);
    }
}

// ---------------- beta / g from hidden (f32) + bf16 copy of hidden ----------------
// wbaT: rows [0,32)=W_b^T, rows [32,64)=W_a^T, each 2048 f32 (pre-transposed).
__global__ __launch_bounds__(256) void k_beta_g(const float* __restrict__ hidden,
                                                const float* __restrict__ wbaT,
                                                const float* __restrict__ dt_bias,
                                                const float* __restrict__ A_log,
                                                float* __restrict__ betab,
                                                float* __restrict__ gbuf,
                                                unsigned short* __restrict__ hidb) {
  const int tid = threadIdx.x;
  const int r = tid >> 5, hh = tid & 31;
  const size_t bt = (size_t)blockIdx.x * 8 + r;
  const float* hrow = hidden + bt * D_;
  const float* wb = wbaT + (size_t)hh * 2048;
  const float* wa = wbaT + (size_t)(32 + hh) * 2048;
  float sb = 0.f, sa = 0.f;
  for (int d = 0; d < D_; d += 4) {
    float4 h4 = *(const float4*)(hrow + d);
    float4 b4 = *(const float4*)(wb + d);
    float4 a4 = *(const float4*)(wa + d);
    sb += h4.x * b4.x; sb += h4.y * b4.y; sb += h4.z * b4.z; sb += h4.w * b4.w;
    sa += h4.x * a4.x; sa += h4.y * a4.y; sa += h4.z * a4.z; sa += h4.w * a4.w;
  }
  // bf16 copy: thread hh handles row slice [hh*64, hh*64+64)
  unsigned short* hb = hidb + bt * D_ + hh * 64;
  #pragma unroll
  for (int d2 = 0; d2 < 64; d2 += 8) {
    float4 v0 = *(const float4*)(hrow + hh * 64 + d2);
    float4 v1 = *(const float4*)(hrow + hh * 64 + d2 + 4);
    u16x8 o = { f2bf(v0.x), f2bf(v0.y), f2bf(v0.z), f2bf(v0.w),
                f2bf(v1.x), f2bf(v1.y), f2bf(v1.z), f2bf(v1.w) };
    *(u16x8*)(hb + d2) = o;
  }
  float beta = 1.f / (1.f + __expf(-sb));
  float xg = sa + dt_bias[hh];
  float sp = (xg > 20.f) ? xg : log1pf(__expf(xg));
  float g = -__expf(A_log[hh]) * sp;
  int b = (int)(bt >> 12);
  int t = (int)(bt & (T_ - 1));
  size_t o = ((size_t)b * HV_ + hh) * T_ + t;
  betab[o] = beta;
  gbuf[o] = g;
}

// ---------------- conv + silu + l2norm for q,k -> qn,kn (b,hk,t,128) bf16 ----------------
__global__ __launch_bounds__(256) void k_qkv(const unsigned short* __restrict__ mqk,
                                             const float* __restrict__ cw,
                                             unsigned short* __restrict__ qn,
                                             unsigned short* __restrict__ kn) {
  const int row = blockIdx.x;          // b*T + t
  const int b = row >> 12, t = row & (T_ - 1);
  const int tid = threadIdx.x;
  const int c0 = tid * 16;
  float4 w[16];
  #pragma unroll
  for (int e = 0; e < 16; ++e) w[e] = *(const float4*)&cw[(size_t)(c0 + e) * 4];
  float acc[16];
  #pragma unroll
  for (int e = 0; e < 16; ++e) acc[e] = 0.f;
  #pragma unroll
  for (int p = 0; p < 4; ++p) {
    int ts = t - 3 + p;
    if (ts < 0) continue;
    const unsigned short* src = mqk + (size_t)(b * T_ + ts) * 4096 + c0;
    u16x8 v0 = *(const u16x8*)src;
    u16x8 v1 = *(const u16x8*)(src + 8);
    #pragma unroll
    for (int e = 0; e < 8; ++e) {
      acc[e]     += bf2f(v0[e]) * ((const float*)&w[e])[p];
      acc[8 + e] += bf2f(v1[e]) * ((const float*)&w[8 + e])[p];
    }
  }
  float s = 0.f;
  #pragma unroll
  for (int e = 0; e < 16; ++e) {
    float x = acc[e];
    x = x / (1.f + __expf(-x));
    acc[e] = x;
    s += x * x;
  }
  s += __shfl_xor(s, 1); s += __shfl_xor(s, 2); s += __shfl_xor(s, 4);
  float sc = rsqrtf(s + 1e-6f);
  bool isq = (c0 < KD_);
  if (isq) sc *= 0.08838834764831845f;   // * 128^-0.5 for q
  int ch = isq ? c0 : (c0 - KD_);
  int hk = ch >> 7, cc = ch & 127;
  unsigned short* dst = (isq ? qn : kn) + ((size_t)(b * 16 + hk) * T_ + t) * 128 + cc;
  u16x8 o0, o1;
  #pragma unroll
  for (int e = 0; e < 8; ++e) { o0[e] = f2bf(acc[e] * sc); o1[e] = f2bf(acc[8 + e] * sc); }
  *(u16x8*)dst = o0;
  *(u16x8*)(dst + 8) = o1;
}

// ---------------- prep: per (b,h,j) T = (I-L)^{-1} bf16 + gj cumsum + knT ----------------
__global__ __launch_bounds__(256) void k_prep(const unsigned short* __restrict__ kn,
                                              const float* __restrict__ gbuf,
                                              const float* __restrict__ betab,
                                              unsigned short* __restrict__ Tg,
                                              unsigned short* __restrict__ knT,
                                              float* __restrict__ gjc) {
  __shared__ __attribute__((aligned(16))) unsigned short kl[CHK][136];
  __shared__ float L[CHK][65];
  __shared__ float W1[CHK][65];
  __shared__ float gj[CHK], bet[CHK];
  const int tid = threadIdx.x;
  const int blk = blockIdx.x;
  const int j = blk & 63, h = (blk >> 6) & 31, b = blk >> 11;
  const int hk = h >> 1;
  const int t0 = j * CHK;
  const int lane = tid & 63, wv = tid >> 6;
  const int fr = lane & 15, kg = lane >> 4;
  const int ty = tid >> 4, tx = tid & 15;

  const unsigned short* ksrc = kn + ((size_t)(b * 16 + hk) * T_ + t0) * 128;
  #pragma unroll
  for (int p = 0; p < 4; ++p) {
    int id = p * 256 + tid;
    int r = id >> 4, c = (id & 15) * 8;
    *(u16x8*)&kl[r][c] = *(const u16x8*)(ksrc + (size_t)r * 128 + c);
  }
  if (tid < 64) {
    float gval = gbuf[((size_t)b * HV_ + h) * T_ + t0 + tid];
    #pragma unroll
    for (int off = 1; off < 64; off <<= 1) {
      float o = __shfl_up(gval, off);
      if (tid >= off) gval += o;
    }
    gj[tid] = gval;
    gjc[((size_t)(b * HV_ + h) * NCH + j) * 64 + tid] = gval;
    bet[tid] = betab[((size_t)b * HV_ + h) * T_ + t0 + tid];
  }
  __syncthreads();

  // knT: h-even blocks store k^T (a-major) for scan's MM6 reg-direct loads
  if ((h & 1) == 0) {
    unsigned short* kd = knT + ((size_t)(b * 16 + hk) * NCH + j) * 8192;
    int a = tid >> 1, l0 = (tid & 1) * 32;
    u16x8 o[4];
    #pragma unroll
    for (int i = 0; i < 32; ++i) ((unsigned short*)o)[i] = kl[l0 + i][a];
    #pragma unroll
    for (int p = 0; p < 4; ++p) *(u16x8*)(kd + a * 64 + l0 + p * 8) = o[p];
  }

  // Gram via MFMA -> L strictly lower
  {
    const int s0 = 16 * wv;
    f32x4 ag[4];
    #pragma unroll
    for (int mt = 0; mt < 4; ++mt) ag[mt] = (f32x4){0.f, 0.f, 0.f, 0.f};
    #pragma unroll
    for (int ks = 0; ks < 4; ++ks) {
      short8 af = *(const short8*)&kl[s0 + fr][ks * 32 + kg * 8];
      #pragma unroll
      for (int mt = 0; mt < 4; ++mt) {
        short8 bfv = *(const short8*)&kl[mt * 16 + fr][ks * 32 + kg * 8];
        ag[mt] = __builtin_amdgcn_mfma_f32_16x16x32_bf16(af, bfv, ag[mt], 0, 0, 0);
      }
    }
    #pragma unroll
    for (int mt = 0; mt < 4; ++mt)
      #pragma unroll
      for (int e = 0; e < 4; ++e) {
        int l = s0 + kg * 4 + e, m = mt * 16 + fr;
        L[l][m] = (l > m) ? (-bet[l] * ag[mt][e] * __expf(gj[l] - gj[m])) : 0.f;
      }
  }
  __syncthreads();
  for (int i = tid; i < CHK * CHK; i += 256) { int l = i >> 6, m = i & 63; W1[l][m] = L[l][m]; }
  __syncthreads();

  // doubling: L(=P) <- (I+L)(I+L^2)...(I+L^32) - I   (r15-proven form)
  #pragma unroll
  for (int dk = 1; dk <= 5; ++dk) {
    const int p2 = 1 << (dk - 1);
    float s4[4][4];
    #pragma unroll
    for (int i = 0; i < 4; ++i)
      #pragma unroll
      for (int c = 0; c < 4; ++c) s4[i][c] = 0.f;
    {
      const int hi = 16 * wv + 15 - p2;
      for (int jm = p2; jm <= hi; ++jm) {
        float wl[4], wr[4];
        #pragma unroll
        for (int i = 0; i < 4; ++i) wl[i] = W1[ty * 4 + i][jm];
        #pragma unroll
        for (int c = 0; c < 4; ++c) wr[c] = W1[jm][tx * 4 + c];
        #pragma unroll
        for (int i = 0; i < 4; ++i)
          #pragma unroll
          for (int c = 0; c < 4; ++c) s4[i][c] += wl[i] * wr[c];
      }
    }
    __syncthreads();
    #pragma unroll
    for (int i = 0; i < 4; ++i)
      #pragma unroll
      for (int c = 0; c < 4; ++c) W1[ty * 4 + i][tx * 4 + c] = s4[i][c];
    __syncthreads();
    float pu[4][4];
    #pragma unroll
    for (int i = 0; i < 4; ++i)
      #pragma unroll
      for (int c = 0; c < 4; ++c) pu[i][c] = L[ty * 4 + i][tx * 4 + c] + W1[ty * 4 + i][tx * 4 + c];
    {
      const int hi = 16 * wv + 14;
      for (int jm = p2 * 2; jm <= hi; ++jm) {
        float pl[4], wr[4];
        #pragma unroll
        for (int i = 0; i < 4; ++i) pl[i] = L[ty * 4 + i][jm];
        #pragma unroll
        for (int c = 0; c < 4; ++c) wr[c] = W1[jm][tx * 4 + c];
        #pragma unroll
        for (int i = 0; i < 4; ++i)
          #pragma unroll
          for (int c = 0; c < 4; ++c) pu[i][c] += pl[i] * wr[c];
      }
    }
    __syncthreads();
    #pragma unroll
    for (int i = 0; i < 4; ++i)
      #pragma unroll
      for (int c = 0; c < 4; ++c) L[ty * 4 + i][tx * 4 + c] = pu[i][c];
    __syncthreads();
  }
  // store T = I + P (bf16)
  unsigned short* td = Tg + (size_t)blk * 4096;
  #pragma unroll
  for (int pp = 0; pp < 2; ++pp) {
    int id = pp * 256 + tid;
    int l = id >> 3, m8 = (id & 7) * 8;
    u16x8 o;
    #pragma unroll
    for (int e = 0; e < 8; ++e) {
      float v = L[l][m8 + e] + ((l == m8 + e) ? 1.f : 0.f);
      o[e] = f2bf(v);
    }
    *(u16x8*)(td + (size_t)l * 64 + m8) = o;
  }
}

// ---------------- scan: XCD-grouped + pipelined kl + reg-direct q/T fragments ----------------
// ql/Tl removed from LDS: per-wave fragments load straight from global (T14 early-issue).
// LDS 46.5 KB -> 3 blocks/CU.
__global__ __launch_bounds__(256) void k_scan(const unsigned short* __restrict__ qn,
                                              const unsigned short* __restrict__ kn,
                                              const unsigned short* __restrict__ mv,
                                              const unsigned short* __restrict__ Tg,
                                              const unsigned short* __restrict__ knT,
                                              const float* __restrict__ gjc,
                                              const float* __restrict__ betab,
                                              const float* __restrict__ cw,
                                              unsigned short* __restrict__ xout) {
  __shared__ __attribute__((aligned(16))) unsigned short kl[CHK][136];
  __shared__ __attribute__((aligned(16))) unsigned short intr[CHK][72];
  __shared__ float ST[16][132];            // S^T (u, a) f32
  __shared__ __attribute__((aligned(16))) unsigned short SbT[16][136];  // bf16 S^T
  __shared__ __attribute__((aligned(16))) unsigned short vbT[16][72], vnT[16][72], vndT[16][72];
  __shared__ float gj[CHK], bet[CHK], eg[CHK], edec[CHK], beg[CHK];

  const int tid = threadIdx.x;
  const int blk = blockIdx.x;
  const int xcd  = blk & 7;
  const int slot = blk >> 3;               // 0..63
  const int g    = xcd + 8 * (slot >> 4);  // 0..31 = b*16 + hk
  const int wgrp = slot & 15;              // 0..15 = h_par*8 + us
  const int b  = g >> 4;
  const int hk = g & 15;
  const int h  = hk * 2 + (wgrp >> 3);
  const int us = wgrp & 7;
  const int u0 = us * 16;
  const int lane = tid & 63, wv = tid >> 6;
  const int fr = lane & 15, kg = lane >> 4;
  const int s0 = 16 * wv;

  const int cvl = tid >> 2, c4 = (tid & 3) * 4;
  float4 wv4[4];
  #pragma unroll
  for (int i = 0; i < 4; ++i)
    wv4[i] = *(const float4*)&cw[(size_t)(2 * KD_ + h * 128 + u0 + c4 + i) * 4];

  for (int i = tid; i < 16 * 132; i += 256) (&ST[0][0])[i] = 0.f;

  const unsigned short* qsrc = qn + (size_t)(b * 16 + hk) * T_ * 128;
  const unsigned short* ksrc = kn + (size_t)(b * 16 + hk) * T_ * 128;
  const unsigned short* tsrc = Tg + (size_t)((b * 32 + h) * 64) * 4096;
  const unsigned short* knsrc = knT + (size_t)(b * 16 + hk) * NCH * 8192;
  const float* gsrc = gjc + (size_t)(b * 32 + h) * 4096;
  const float* bsrc = betab + ((size_t)b * HV_ + h) * T_;

  const int rr = tid >> 4, cc8 = (tid & 15) * 8;  // kl slots

  // pipeline registers (chunk j+1)
  u16x8 krg[4];
  u16x4 vld[4];
  float g_r = 0.f, b_r = 0.f;

  // ---- prologue: load + write chunk 0 (kl, gj, bet) ----
  #pragma unroll
  for (int p = 0; p < 4; ++p) {
    int r = p * 16 + rr;
    krg[p] = *(const u16x8*)(ksrc + (size_t)r * 128 + cc8);
  }
  if (tid < 64) { g_r = gsrc[tid]; b_r = bsrc[tid]; }
  #pragma unroll
  for (int p = 0; p < 4; ++p) {
    int ts = cvl - 3 + p;
    vld[p] = (ts >= 0) ? *(const u16x4*)(mv + (size_t)(b * T_ + ts) * 4096 + h * 128 + u0 + c4)
                       : (u16x4){0, 0, 0, 0};
  }
  #pragma unroll
  for (int p = 0; p < 4; ++p) {
    int r = p * 16 + rr;
    *(u16x8*)&kl[r][cc8] = krg[p];
  }
  if (tid < 64) { gj[tid] = g_r; bet[tid] = b_r; }
  __syncthreads();   // chunk-0 data + ST zero visible

  for (int j = 0; j < NCH; ++j) {
    const int t0 = j * CHK;
    // reg-direct fragments for chunk j (issued early, in flight across top compute):
    // kr: MM6 B-operand from knT; qf: q fragments (MM0/MM5 A); tf: T fragments (MM2 A)
    short8 kr[2][2], qf[4], tf[2];
    #pragma unroll
    for (int t2 = 0; t2 < 2; ++t2) {
      int a0 = wv * 32 + t2 * 16;
      #pragma unroll
      for (int ks = 0; ks < 2; ++ks)
        kr[t2][ks] = *(const short8*)(knsrc + (size_t)j * 8192 + (a0 + fr) * 64 + ks * 32 + kg * 8);
    }
    #pragma unroll
    for (int ks = 0; ks < 4; ++ks)
      qf[ks] = *(const short8*)(qsrc + (size_t)(t0 + s0 + fr) * 128 + ks * 32 + kg * 8);
    #pragma unroll
    for (int ks = 0; ks < 2; ++ks)
      tf[ks] = *(const short8*)(tsrc + (size_t)j * 4096 + (s0 + fr) * 64 + ks * 32 + kg * 8);
    // prefetch chunk j+1 kl tiles into regs (T14 issue-early)
    if (j + 1 < NCH) {
      const int t1 = t0 + CHK;
      #pragma unroll
      for (int p = 0; p < 4; ++p) {
        int r = p * 16 + rr;
        krg[p] = *(const u16x8*)(ksrc + (size_t)(t1 + r) * 128 + cc8);
      }
      if (tid < 64) { g_r = gsrc[(j + 1) * 64 + tid]; b_r = bsrc[t1 + tid]; }
    }
    // top compute (chunk j): eg/edec/beg, conv from vld regs, SbT
    if (tid < 64) {
      float gl = gj[63];
      float e = __expf(gj[tid]);
      eg[tid] = e;
      edec[tid] = __expf(gl - gj[tid]);
      beg[tid] = bet[tid] * e;
    }
    {
      float a4[4] = {0.f, 0.f, 0.f, 0.f};
      #pragma unroll
      for (int p = 0; p < 4; ++p)
        #pragma unroll
        for (int i = 0; i < 4; ++i) a4[i] += bf2f(vld[p][i]) * ((const float*)&wv4[i])[p];
      float be = bet[cvl];
      #pragma unroll
      for (int i = 0; i < 4; ++i) {
        float x = a4[i];
        x = x / (1.f + __expf(-x)) * be;
        vbT[c4 + i][cvl] = f2bf(x);
      }
    }
    // prefetch conv-v for chunk j+1
    if (j + 1 < NCH) {
      #pragma unroll
      for (int p = 0; p < 4; ++p) {
        int ts = t0 + CHK + cvl - 3 + p;
        vld[p] = *(const u16x4*)(mv + (size_t)(b * T_ + ts) * 4096 + h * 128 + u0 + c4);
      }
    }
    // SbT = bf16(S^T)
    {
      int u = tid >> 4, a8 = (tid & 15) * 8;
      u16x8 o;
      #pragma unroll
      for (int e = 0; e < 8; ++e) o[e] = f2bf(ST[u][a8 + e]);
      *(u16x8*)&SbT[u][a8] = o;
    }
    __syncthreads();   // barrier2: vbT/SbT/eg/edec/beg ready

    // MM0: Gram q@k^T -> intra (masked, decayed)  [A = qf regs, B = kl LDS]
    {
      f32x4 ag[4];
      #pragma unroll
      for (int mt = 0; mt < 4; ++mt) ag[mt] = (f32x4){0.f, 0.f, 0.f, 0.f};
      #pragma unroll
      for (int ks = 0; ks < 4; ++ks) {
        #pragma unroll
        for (int mt = 0; mt < 4; ++mt) {
          short8 bfv = *(const short8*)&kl[mt * 16 + fr][ks * 32 + kg * 8];
          ag[mt] = __builtin_amdgcn_mfma_f32_16x16x32_bf16(qf[ks], bfv, ag[mt], 0, 0, 0);
        }
      }
      #pragma unroll
      for (int mt = 0; mt < 4; ++mt)
        #pragma unroll
        for (int e = 0; e < 4; ++e) {
          int l = s0 + kg * 4 + e, m = mt * 16 + fr;
          float v = (l >= m) ? (ag[mt][e] * __expf(gj[l] - gj[m])) : 0.f;
          intr[l][m] = f2bf(v);
        }
    }
    // MM1: KS = k@S ; vmr = vb - beg*KS (in place over vbT)
    {
      f32x4 a1 = (f32x4){0.f, 0.f, 0.f, 0.f};
      #pragma unroll
      for (int ks = 0; ks < 4; ++ks) {
        short8 af = *(const short8*)&kl[s0 + fr][ks * 32 + kg * 8];
        short8 bfv = *(const short8*)&SbT[fr][ks * 32 + kg * 8];
        a1 = __builtin_amdgcn_mfma_f32_16x16x32_bf16(af, bfv, a1, 0, 0, 0);
      }
      #pragma unroll
      for (int e = 0; e < 4; ++e) {
        int l = s0 + kg * 4 + e;
        float vm = bf2f(vbT[fr][l]) - beg[l] * a1[e];
        vbT[fr][l] = f2bf(vm);
      }
    }
    __syncthreads();   // barrier3
    // MM2: v_new = T @ vmr ; also vndT = v_new * edec  [A = tf regs]
    {
      f32x4 a2 = (f32x4){0.f, 0.f, 0.f, 0.f};
      #pragma unroll
      for (int ks = 0; ks < 2; ++ks) {
        short8 bfv = *(const short8*)&vbT[fr][ks * 32 + kg * 8];
        a2 = __builtin_amdgcn_mfma_f32_16x16x32_bf16(tf[ks], bfv, a2, 0, 0, 0);
      }
      #pragma unroll
      for (int e = 0; e < 4; ++e) {
        int l = s0 + kg * 4 + e;
        vnT[fr][l]  = f2bf(a2[e]);
        vndT[fr][l] = f2bf(a2[e] * edec[l]);
      }
    }
    __syncthreads();   // barrier4
    // MM4: intra@v_new ; MM5: q@S ; out
    {
      f32x4 ai = (f32x4){0.f, 0.f, 0.f, 0.f};
      f32x4 aq = (f32x4){0.f, 0.f, 0.f, 0.f};
      #pragma unroll
      for (int ks = 0; ks < 2; ++ks) {
        short8 af = *(const short8*)&intr[s0 + fr][ks * 32 + kg * 8];
        short8 bfv = *(const short8*)&vnT[fr][ks * 32 + kg * 8];
        ai = __builtin_amdgcn_mfma_f32_16x16x32_bf16(af, bfv, ai, 0, 0, 0);
      }
      #pragma unroll
      for (int ks = 0; ks < 4; ++ks) {
        short8 bfv = *(const short8*)&SbT[fr][ks * 32 + kg * 8];
        aq = __builtin_amdgcn_mfma_f32_16x16x32_bf16(qf[ks], bfv, aq, 0, 0, 0);
      }
      #pragma unroll
      for (int e = 0; e < 4; ++e) {
        int l = s0 + kg * 4 + e;
        float o = eg[l] * aq[e] + ai[e];
        xout[((size_t)(b * T_ + t0 + l) * HV_ + h) * UV_ + u0 + fr] = f2bf(o);
      }
    }
    // MM6 (MFMA): S^T = eg[63]*S^T + (v_new*edec) @ k^T  [A=vndT (LDS), B=kr (regs)]
    {
      float egl = eg[63];
      #pragma unroll
      for (int t2 = 0; t2 < 2; ++t2) {
        int a0 = wv * 32 + t2 * 16;
        f32x4 cf;
        #pragma unroll
        for (int e = 0; e < 4; ++e) cf[e] = ST[kg * 4 + e][a0 + fr] * egl;
        #pragma unroll
        for (int ks = 0; ks < 2; ++ks) {
          short8 af = *(const short8*)&vndT[fr][ks * 32 + kg * 8];
          cf = __builtin_amdgcn_mfma_f32_16x16x32_bf16(af, kr[t2][ks], cf, 0, 0, 0);
        }
        #pragma unroll
        for (int e = 0; e < 4; ++e) ST[kg * 4 + e][a0 + fr] = cf[e];
      }
    }
    __syncthreads();   // end-of-chunk: all reads of kl/gj/bet done
    // T14 write-late: dump chunk j+1 kl regs into LDS
    if (j + 1 < NCH) {
      #pragma unroll
      for (int p = 0; p < 4; ++p) {
        int r = p * 16 + rr;
        *(u16x8*)&kl[r][cc8] = krg[p];
      }
      if (tid < 64) { gj[tid] = g_r; bet[tid] = b_r; }
    }
    __syncthreads();   // barrier1': chunk j+1 data visible
  }
}

// ---------------- x * silu(z) -> RMSNorm -> bf16 ----------------
__global__ __launch_bounds__(256) void k_gate_norm(const unsigned short* __restrict__ x,
                                                   const unsigned short* __restrict__ z,
                                                   const float* __restrict__ nw,
                                                   unsigned short* __restrict__ out) {
  const int row = blockIdx.x * 4 + (threadIdx.x >> 6);
  const int lane = threadIdx.x & 63;
  const unsigned short* xp = x + (size_t)row * UV_;
  const unsigned short* zp = z + (size_t)row * UV_;
  float x0 = bf2f(xp[lane]), x1 = bf2f(xp[lane + 64]);
  float z0 = bf2f(zp[lane]), z1 = bf2f(zp[lane + 64]);
  float g0 = x0 * (z0 / (1.f + __expf(-z0)));
  float g1 = x1 * (z1 / (1.f + __expf(-z1)));
  float s = g0 * g0 + g1 * g1;
  #pragma unroll
  for (int off = 32; off > 0; off >>= 1) s += __shfl_xor(s, off);
  float r = rsqrtf(s * (1.f / UV_) + 1e-6f);
  out[(size_t)row * UV_ + lane]      = f2bf(nw[lane] * g0 * r);
  out[(size_t)row * UV_ + lane + 64] = f2bf(nw[lane + 64] * g1 * r);
}

// ---------------- launcher ----------------
extern "C" void kernel_launch(void* const* d_in, const int* in_sizes, int n_in,
                              void* d_out, int out_size, void* d_ws, size_t ws_size,
                              hipStream_t stream) {
  (void)in_sizes; (void)n_in; (void)out_size; (void)ws_size;
  const float* hidden  = (const float*)d_in[0];
  const float* W_qkv   = (const float*)d_in[1];
  const float* W_z     = (const float*)d_in[2];
  const float* W_b     = (const float*)d_in[3];
  const float* W_a     = (const float*)d_in[4];
  const float* conv_w  = (const float*)d_in[5];
  const float* dt_bias = (const float*)d_in[6];
  const float* A_log   = (const float*)d_in[7];
  const float* norm_w  = (const float*)d_in[8];
  const float* W_out   = (const float*)d_in[9];
  float* out = (float*)d_out;

  // workspace layout — NOTE: [256,288) MiB is NEVER touched (crash zone, r1/r4/r7/r14).
  //  [  0, 32) wqkvT (->G1)          then Tg   (prep -> scan)
  //  [ 32, 96) wbaT (0.5MB scratch, beta_g) then mqk (G1 -> k_qkv), then xcore
  //  [ 96,160) mv   (G1 -> scan)     then normed (gate_norm -> Gout)
  //  [160,192) hidb (beta_g -> mqk/mv GEMMs), then qn (k_qkv -> scan), then zb [160,224)
  //  [192,224) knT  (prep -> scan)
  //  [224,256) kn   (k_qkv -> scan)  then wzT [224,240) + woutT [240,256)
  //  [288,289) betab  [289,290) gbuf  [290,291) gjc   (proven slots)
  const size_t MB = 1048576ull;
  char* w = (char*)d_ws;
  unsigned short* wqkvT = (unsigned short*)(w);
  unsigned short* Tg    = (unsigned short*)(w);
  float*          wbaT  = (float*)(w + 32 * MB);
  unsigned short* mqk   = (unsigned short*)(w + 32 * MB);
  unsigned short* xcore = (unsigned short*)(w + 32 * MB);
  unsigned short* mv    = (unsigned short*)(w + 96 * MB);
  unsigned short* normed= (unsigned short*)(w + 96 * MB);
  unsigned short* hidb  = (unsigned short*)(w + 160 * MB);
  unsigned short* qn    = (unsigned short*)(w + 160 * MB);
  unsigned short* zb    = (unsigned short*)(w + 160 * MB);
  unsigned short* knT   = (unsigned short*)(w + 192 * MB);
  unsigned short* kn    = (unsigned short*)(w + 224 * MB);
  unsigned short* wzT   = (unsigned short*)(w + 224 * MB);
  unsigned short* woutT = (unsigned short*)(w + 240 * MB);
  float*          betab = (float*)(w + 288 * MB);
  float*          gbuf  = (float*)(w + 289 * MB);
  float*          gjc   = (float*)(w + 290 * MB);

  // 0. W_b/W_a -> f32 transposed (scratch in pre-GEMM mqk region)
  k_transpose_f32<<<dim3(D_ / 32, 1), dim3(32, 8), 0, stream>>>(W_b, wbaT, D_, 32);
  k_transpose_f32<<<dim3(D_ / 32, 1), dim3(32, 8), 0, stream>>>(W_a, wbaT + 32 * 2048, D_, 32);
  // 1. beta/g + bf16 hidden (vectorized via wbaT; hidb lives until the two big GEMMs)
  k_beta_g<<<dim3(B_ * T_ / 8), 256, 0, stream>>>(hidden, wbaT, dt_bias, A_log, betab, gbuf, hidb);
  // 2. W_qkv^T
  k_transpose<<<dim3(D_ / 32, CD_ / 32), dim3(32, 8), 0, stream>>>(W_qkv, wqkvT, D_, CD_);
  // 3. mqk | mv = hidb @ W_qkv halves (full gload, BK=64)  — hidb dead after; mqk overwrites wbaT
  k_gemm<true, unsigned short><<<dim3(64 * 16), 256, 0, stream>>>(hidb, wqkvT, mqk, 4096, 2048);
  k_gemm<true, unsigned short><<<dim3(64 * 16), 256, 0, stream>>>(hidb, wqkvT + (size_t)4096 * 2048, mv, 4096, 2048);
  // 4. q/k conv+silu+l2norm (qn overwrites dead hidb region)
  k_qkv<<<dim3(B_ * T_), 256, 0, stream>>>(mqk, conv_w, qn, kn);
  // 5. prep: T matrices + gj cumsum + knT
  k_prep<<<dim3(B_ * HV_ * NCH), 256, 0, stream>>>(kn, gbuf, betab, Tg, knT, gjc);
  // 6. scan (XCD-grouped decode + pipelined staging + reg-direct q/T)
  k_scan<<<dim3(B_ * HV_ * 8), 256, 0, stream>>>(qn, kn, mv, Tg, knT, gjc, betab, conv_w, xcore);
  // 7. z path (f32-A GEMM reads d_in hidden directly; into regions freed by scan)
  k_transpose<<<dim3(D_ / 32, VD_ / 32), dim3(32, 8), 0, stream>>>(W_z, wzT, D_, VD_);
  k_gemm<false, unsigned short><<<dim3(64 * 16), 256, 0, stream>>>(hidden, wzT, zb, 4096, 2048);
  k_transpose<<<dim3(VD_ / 32, D_ / 32), dim3(32, 8), 0, stream>>>(W_out, woutT, VD_, D_);
  // 8. gate + RMSNorm
  k_gate_norm<<<dim3(B_ * T_ * HV_ / 4), 256, 0, stream>>>(xcore, zb, norm_w, normed);
  // 9. out = normed @ W_out (full gload)
  k_gemm<true, float><<<dim3(64 * 8), 256, 0, stream>>>(normed, woutT, out, 2048, 4096);
}

// Round 20
// 1601.298 us; speedup vs baseline: 1.1729x; 1.1729x over previous
//
#include <hip/hip_runtime.h>

// ---------------- problem constants ----------------
#define B_   2
#define T_   4096
#define D_   2048
#define HV_  32
#define AK_  128
#define UV_  128
#define KD_  2048          // KEY_DIM
#define VD_  4096          // VALUE_DIM
#define CD_  8192          // CONV_DIM
#define CHK  64            // chunk size
#define NCH  (T_/CHK)      // 64 chunks

typedef __attribute__((ext_vector_type(4))) float  f32x4;
typedef __attribute__((ext_vector_type(8))) short  short8;
typedef __attribute__((ext_vector_type(4))) short  short4b;
typedef __attribute__((ext_vector_type(8))) unsigned short u16x8;
typedef __attribute__((ext_vector_type(4))) unsigned short u16x4;

__device__ __forceinline__ float bf2f(unsigned short u) {
  return __uint_as_float(((unsigned)u) << 16);
}
__device__ __forceinline__ unsigned short f2bf(float f) { // RNE
  unsigned u = __float_as_uint(f);
  return (unsigned short)((u + 0x7fffu + ((u >> 16) & 1u)) >> 16);
}
__device__ __forceinline__ void gload16(const void* g, void* l) {
  __builtin_amdgcn_global_load_lds((const __attribute__((address_space(1))) void*)g,
                                   (__attribute__((address_space(3))) void*)l, 16, 0, 0);
}

// ---------------- transpose f32 (K,N) -> bf16 (N,K) ----------------
__global__ __launch_bounds__(256) void k_transpose(const float* __restrict__ src,
                                                   unsigned short* __restrict__ dst,
                                                   int K, int N) {
  __shared__ float tile[32][33];
  int k0 = blockIdx.x * 32, n0 = blockIdx.y * 32;
  int tx = threadIdx.x, ty = threadIdx.y;
  #pragma unroll
  for (int i = 0; i < 32; i += 8)
    tile[ty + i][tx] = src[(size_t)(k0 + ty + i) * N + n0 + tx];
  __syncthreads();
  #pragma unroll
  for (int i = 0; i < 32; i += 8)
    dst[(size_t)(n0 + ty + i) * K + k0 + tx] = f2bf(tile[tx][ty + i]);
}

// ---------------- MFMA GEMM, 128x256 tile, BK=64, band/XCD-swizzled (r15-proven) ----------------
__device__ __forceinline__ void storeC(float* p, float v) { *p = v; }
__device__ __forceinline__ void storeC(unsigned short* p, float v) { *p = f2bf(v); }

template <bool AGL, typename CT>
__global__ __launch_bounds__(256, 2) void k_gemm(const void* __restrict__ Av,
                                                 const unsigned short* __restrict__ BT,
                                                 CT* __restrict__ C, int N, int K) {
  __shared__ __attribute__((aligned(16))) short As[128 * 64];
  __shared__ __attribute__((aligned(16))) short Bs[256 * 64];
  const int tid  = threadIdx.x;
  const int bid  = blockIdx.x;
  const int tb   = bid & 63;
  const size_t bm = (size_t)(8 * (tb & 7) + (tb >> 3)) * 128;
  const size_t bn = (size_t)(bid >> 6) * 256;
  const int lane = tid & 63;
  const int wave = tid >> 6;
  const int wm = (wave >> 1) * 64;
  const int wn = (wave & 1) * 64;
  const int fr = lane & 15;
  const int kg = lane >> 4;
  const int lr = lane >> 3, lc8 = (lane & 7) * 8;
  const short* gb = (const short*)BT + (bn + wave * 64 + lr) * (size_t)K + lc8;
  short* lB = &Bs[wave * 64 * 64];
  const short* gab = (const short*)Av + (bm + wave * 32 + lr) * (size_t)K + lc8; // AGL path
  short* lA = &As[wave * 32 * 64];

  f32x4 acc[4][8];
  #pragma unroll
  for (int i = 0; i < 4; ++i)
    #pragma unroll
    for (int j2 = 0; j2 < 8; ++j2) acc[i][j2] = (f32x4){0.f, 0.f, 0.f, 0.f};

  for (int kt = 0; kt < K; kt += 64) {
    __syncthreads();
    #pragma unroll
    for (int p = 0; p < 8; ++p)
      gload16(gb + kt + (size_t)(8 * p) * K, lB + (8 * p) * 64);
    if constexpr (AGL) {
      #pragma unroll
      for (int p = 0; p < 4; ++p)
        gload16(gab + kt + (size_t)(8 * p) * K, lA + (8 * p) * 64);
    } else {
      const float* Ag = (const float*)Av + bm * (size_t)K;
      #pragma unroll
      for (int s = 0; s < 8; ++s) {
        int ch = s * 256 + tid;
        int r = ch >> 4, c4 = (ch & 15) * 4;
        float4 v = *(const float4*)(Ag + (size_t)r * K + kt + c4);
        short4b sv = { (short)f2bf(v.x), (short)f2bf(v.y), (short)f2bf(v.z), (short)f2bf(v.w) };
        *(short4b*)&As[r * 64 + c4] = sv;
      }
    }
    __syncthreads();
    #pragma unroll
    for (int kk = 0; kk < 2; ++kk) {
      short8 af[4], bfr[8];
      #pragma unroll
      for (int mi = 0; mi < 4; ++mi) af[mi] = *(const short8*)&As[(wm + mi*16 + fr)*64 + kk*32 + kg*8];
      #pragma unroll
      for (int ni = 0; ni < 4; ++ni) {
        bfr[ni]     = *(const short8*)&Bs[(wn + ni*16 + fr)*64 + kk*32 + kg*8];
        bfr[4 + ni] = *(const short8*)&Bs[(128 + wn + ni*16 + fr)*64 + kk*32 + kg*8];
      }
      #pragma unroll
      for (int mi = 0; mi < 4; ++mi)
        #pragma unroll
        for (int ni = 0; ni < 8; ++ni)
          acc[mi][ni] = __builtin_amdgcn_mfma_f32_16x16x32_bf16(af[mi], bfr[ni], acc[mi][ni], 0, 0, 0);
    }
  }
  #pragma unroll
  for (int mi = 0; mi < 4; ++mi)
    #pragma unroll
    for (int ni = 0; ni < 8; ++ni) {
      size_t row = bm + wm + mi * 16 + kg * 4;
      size_t col = bn + (ni >= 4 ? 128 : 0) + wn + (ni & 3) * 16 + fr;
      #pragma unroll
      for (int e = 0; e < 4; ++e) storeC(&C[(row + e) * (size_t)N + col], acc[mi][ni][e]);
    }
}

// ---------------- beta / g from hidden (r18-proven coalesced form) + bf16 copy ----------------
__global__ __launch_bounds__(256) void k_beta_g(const float* __restrict__ hidden,
                                                const float* __restrict__ Wb,
                                                const float* __restrict__ Wa,
                                                const float* __restrict__ dt_bias,
                                                const float* __restrict__ A_log,
                                                float* __restrict__ betab,
                                                float* __restrict__ gbuf,
                                                unsigned short* __restrict__ hidb) {
  const int tid = threadIdx.x;
  const int r = tid >> 5, hh = tid & 31;
  const size_t bt = (size_t)blockIdx.x * 8 + r;
  const float* hrow = hidden + bt * D_;
  float sb = 0.f, sa = 0.f;
  for (int d = 0; d < D_; ++d) {
    float hv = hrow[d];
    sb += hv * Wb[d * 32 + hh];      // coalesced across the 32 hh lanes
    sa += hv * Wa[d * 32 + hh];
  }
  // bf16 copy: thread hh handles row slice [hh*64, hh*64+64)
  unsigned short* hb = hidb + bt * D_ + hh * 64;
  #pragma unroll
  for (int d2 = 0; d2 < 64; d2 += 8) {
    float4 v0 = *(const float4*)(hrow + hh * 64 + d2);
    float4 v1 = *(const float4*)(hrow + hh * 64 + d2 + 4);
    u16x8 o = { f2bf(v0.x), f2bf(v0.y), f2bf(v0.z), f2bf(v0.w),
                f2bf(v1.x), f2bf(v1.y), f2bf(v1.z), f2bf(v1.w) };
    *(u16x8*)(hb + d2) = o;
  }
  float beta = 1.f / (1.f + __expf(-sb));
  float xg = sa + dt_bias[hh];
  float sp = (xg > 20.f) ? xg : log1pf(__expf(xg));
  float g = -__expf(A_log[hh]) * sp;
  int b = (int)(bt >> 12);
  int t = (int)(bt & (T_ - 1));
  size_t o = ((size_t)b * HV_ + hh) * T_ + t;
  betab[o] = beta;
  gbuf[o] = g;
}

// ---------------- conv + silu + l2norm for q,k -> qn,kn (b,hk,t,128) bf16 ----------------
__global__ __launch_bounds__(256) void k_qkv(const unsigned short* __restrict__ mqk,
                                             const float* __restrict__ cw,
                                             unsigned short* __restrict__ qn,
                                             unsigned short* __restrict__ kn) {
  const int row = blockIdx.x;          // b*T + t
  const int b = row >> 12, t = row & (T_ - 1);
  const int tid = threadIdx.x;
  const int c0 = tid * 16;
  float4 w[16];
  #pragma unroll
  for (int e = 0; e < 16; ++e) w[e] = *(const float4*)&cw[(size_t)(c0 + e) * 4];
  float acc[16];
  #pragma unroll
  for (int e = 0; e < 16; ++e) acc[e] = 0.f;
  #pragma unroll
  for (int p = 0; p < 4; ++p) {
    int ts = t - 3 + p;
    if (ts < 0) continue;
    const unsigned short* src = mqk + (size_t)(b * T_ + ts) * 4096 + c0;
    u16x8 v0 = *(const u16x8*)src;
    u16x8 v1 = *(const u16x8*)(src + 8);
    #pragma unroll
    for (int e = 0; e < 8; ++e) {
      acc[e]     += bf2f(v0[e]) * ((const float*)&w[e])[p];
      acc[8 + e] += bf2f(v1[e]) * ((const float*)&w[8 + e])[p];
    }
  }
  float s = 0.f;
  #pragma unroll
  for (int e = 0; e < 16; ++e) {
    float x = acc[e];
    x = x / (1.f + __expf(-x));
    acc[e] = x;
    s += x * x;
  }
  s += __shfl_xor(s, 1); s += __shfl_xor(s, 2); s += __shfl_xor(s, 4);
  float sc = rsqrtf(s + 1e-6f);
  bool isq = (c0 < KD_);
  if (isq) sc *= 0.08838834764831845f;   // * 128^-0.5 for q
  int ch = isq ? c0 : (c0 - KD_);
  int hk = ch >> 7, cc = ch & 127;
  unsigned short* dst = (isq ? qn : kn) + ((size_t)(b * 16 + hk) * T_ + t) * 128 + cc;
  u16x8 o0, o1;
  #pragma unroll
  for (int e = 0; e < 8; ++e) { o0[e] = f2bf(acc[e] * sc); o1[e] = f2bf(acc[8 + e] * sc); }
  *(u16x8*)dst = o0;
  *(u16x8*)(dst + 8) = o1;
}

// ---------------- prep: per (b,h,j) T = (I-L)^{-1} bf16 + gj cumsum + knT ----------------
__global__ __launch_bounds__(256) void k_prep(const unsigned short* __restrict__ kn,
                                              const float* __restrict__ gbuf,
                                              const float* __restrict__ betab,
                                              unsigned short* __restrict__ Tg,
                                              unsigned short* __restrict__ knT,
                                              float* __restrict__ gjc) {
  __shared__ __attribute__((aligned(16))) unsigned short kl[CHK][136];
  __shared__ float L[CHK][65];
  __shared__ float W1[CHK][65];
  __shared__ float gj[CHK], bet[CHK];
  const int tid = threadIdx.x;
  const int blk = blockIdx.x;
  const int j = blk & 63, h = (blk >> 6) & 31, b = blk >> 11;
  const int hk = h >> 1;
  const int t0 = j * CHK;
  const int lane = tid & 63, wv = tid >> 6;
  const int fr = lane & 15, kg = lane >> 4;
  const int ty = tid >> 4, tx = tid & 15;

  const unsigned short* ksrc = kn + ((size_t)(b * 16 + hk) * T_ + t0) * 128;
  #pragma unroll
  for (int p = 0; p < 4; ++p) {
    int id = p * 256 + tid;
    int r = id >> 4, c = (id & 15) * 8;
    *(u16x8*)&kl[r][c] = *(const u16x8*)(ksrc + (size_t)r * 128 + c);
  }
  if (tid < 64) {
    float gval = gbuf[((size_t)b * HV_ + h) * T_ + t0 + tid];
    #pragma unroll
    for (int off = 1; off < 64; off <<= 1) {
      float o = __shfl_up(gval, off);
      if (tid >= off) gval += o;
    }
    gj[tid] = gval;
    gjc[((size_t)(b * HV_ + h) * NCH + j) * 64 + tid] = gval;
    bet[tid] = betab[((size_t)b * HV_ + h) * T_ + t0 + tid];
  }
  __syncthreads();

  // knT: h-even blocks store k^T (a-major) for scan's MM6 reg-direct loads
  if ((h & 1) == 0) {
    unsigned short* kd = knT + ((size_t)(b * 16 + hk) * NCH + j) * 8192;
    int a = tid >> 1, l0 = (tid & 1) * 32;
    u16x8 o[4];
    #pragma unroll
    for (int i = 0; i < 32; ++i) ((unsigned short*)o)[i] = kl[l0 + i][a];
    #pragma unroll
    for (int p = 0; p < 4; ++p) *(u16x8*)(kd + a * 64 + l0 + p * 8) = o[p];
  }

  // Gram via MFMA -> L strictly lower
  {
    const int s0 = 16 * wv;
    f32x4 ag[4];
    #pragma unroll
    for (int mt = 0; mt < 4; ++mt) ag[mt] = (f32x4){0.f, 0.f, 0.f, 0.f};
    #pragma unroll
    for (int ks = 0; ks < 4; ++ks) {
      short8 af = *(const short8*)&kl[s0 + fr][ks * 32 + kg * 8];
      #pragma unroll
      for (int mt = 0; mt < 4; ++mt) {
        short8 bfv = *(const short8*)&kl[mt * 16 + fr][ks * 32 + kg * 8];
        ag[mt] = __builtin_amdgcn_mfma_f32_16x16x32_bf16(af, bfv, ag[mt], 0, 0, 0);
      }
    }
    #pragma unroll
    for (int mt = 0; mt < 4; ++mt)
      #pragma unroll
      for (int e = 0; e < 4; ++e) {
        int l = s0 + kg * 4 + e, m = mt * 16 + fr;
        L[l][m] = (l > m) ? (-bet[l] * ag[mt][e] * __expf(gj[l] - gj[m])) : 0.f;
      }
  }
  __syncthreads();
  for (int i = tid; i < CHK * CHK; i += 256) { int l = i >> 6, m = i & 63; W1[l][m] = L[l][m]; }
  __syncthreads();

  // doubling: L(=P) <- (I+L)(I+L^2)...(I+L^32) - I   (r15-proven form)
  #pragma unroll
  for (int dk = 1; dk <= 5; ++dk) {
    const int p2 = 1 << (dk - 1);
    float s4[4][4];
    #pragma unroll
    for (int i = 0; i < 4; ++i)
      #pragma unroll
      for (int c = 0; c < 4; ++c) s4[i][c] = 0.f;
    {
      const int hi = 16 * wv + 15 - p2;
      for (int jm = p2; jm <= hi; ++jm) {
        float wl[4], wr[4];
        #pragma unroll
        for (int i = 0; i < 4; ++i) wl[i] = W1[ty * 4 + i][jm];
        #pragma unroll
        for (int c = 0; c < 4; ++c) wr[c] = W1[jm][tx * 4 + c];
        #pragma unroll
        for (int i = 0; i < 4; ++i)
          #pragma unroll
          for (int c = 0; c < 4; ++c) s4[i][c] += wl[i] * wr[c];
      }
    }
    __syncthreads();
    #pragma unroll
    for (int i = 0; i < 4; ++i)
      #pragma unroll
      for (int c = 0; c < 4; ++c) W1[ty * 4 + i][tx * 4 + c] = s4[i][c];
    __syncthreads();
    float pu[4][4];
    #pragma unroll
    for (int i = 0; i < 4; ++i)
      #pragma unroll
      for (int c = 0; c < 4; ++c) pu[i][c] = L[ty * 4 + i][tx * 4 + c] + W1[ty * 4 + i][tx * 4 + c];
    {
      const int hi = 16 * wv + 14;
      for (int jm = p2 * 2; jm <= hi; ++jm) {
        float pl[4], wr[4];
        #pragma unroll
        for (int i = 0; i < 4; ++i) pl[i] = L[ty * 4 + i][jm];
        #pragma unroll
        for (int c = 0; c < 4; ++c) wr[c] = W1[jm][tx * 4 + c];
        #pragma unroll
        for (int i = 0; i < 4; ++i)
          #pragma unroll
          for (int c = 0; c < 4; ++c) pu[i][c] += pl[i] * wr[c];
      }
    }
    __syncthreads();
    #pragma unroll
    for (int i = 0; i < 4; ++i)
      #pragma unroll
      for (int c = 0; c < 4; ++c) L[ty * 4 + i][tx * 4 + c] = pu[i][c];
    __syncthreads();
  }
  // store T = I + P (bf16)
  unsigned short* td = Tg + (size_t)blk * 4096;
  #pragma unroll
  for (int pp = 0; pp < 2; ++pp) {
    int id = pp * 256 + tid;
    int l = id >> 3, m8 = (id & 7) * 8;
    u16x8 o;
    #pragma unroll
    for (int e = 0; e < 8; ++e) {
      float v = L[l][m8 + e] + ((l == m8 + e) ? 1.f : 0.f);
      o[e] = f2bf(v);
    }
    *(u16x8*)(td + (size_t)l * 64 + m8) = o;
  }
}

// ---------------- scan: XCD-grouped + pipelined kl + reg-direct q/T fragments (r19) ----------------
__global__ __launch_bounds__(256) void k_scan(const unsigned short* __restrict__ qn,
                                              const unsigned short* __restrict__ kn,
                                              const unsigned short* __restrict__ mv,
                                              const unsigned short* __restrict__ Tg,
                                              const unsigned short* __restrict__ knT,
                                              const float* __restrict__ gjc,
                                              const float* __restrict__ betab,
                                              const float* __restrict__ cw,
                                              unsigned short* __restrict__ xout) {
  __shared__ __attribute__((aligned(16))) unsigned short kl[CHK][136];
  __shared__ __attribute__((aligned(16))) unsigned short intr[CHK][72];
  __shared__ float ST[16][132];            // S^T (u, a) f32
  __shared__ __attribute__((aligned(16))) unsigned short SbT[16][136];  // bf16 S^T
  __shared__ __attribute__((aligned(16))) unsigned short vbT[16][72], vnT[16][72], vndT[16][72];
  __shared__ float gj[CHK], bet[CHK], eg[CHK], edec[CHK], beg[CHK];

  const int tid = threadIdx.x;
  const int blk = blockIdx.x;
  const int xcd  = blk & 7;
  const int slot = blk >> 3;               // 0..63
  const int g    = xcd + 8 * (slot >> 4);  // 0..31 = b*16 + hk
  const int wgrp = slot & 15;              // 0..15 = h_par*8 + us
  const int b  = g >> 4;
  const int hk = g & 15;
  const int h  = hk * 2 + (wgrp >> 3);
  const int us = wgrp & 7;
  const int u0 = us * 16;
  const int lane = tid & 63, wv = tid >> 6;
  const int fr = lane & 15, kg = lane >> 4;
  const int s0 = 16 * wv;

  const int cvl = tid >> 2, c4 = (tid & 3) * 4;
  float4 wv4[4];
  #pragma unroll
  for (int i = 0; i < 4; ++i)
    wv4[i] = *(const float4*)&cw[(size_t)(2 * KD_ + h * 128 + u0 + c4 + i) * 4];

  for (int i = tid; i < 16 * 132; i += 256) (&ST[0][0])[i] = 0.f;

  const unsigned short* qsrc = qn + (size_t)(b * 16 + hk) * T_ * 128;
  const unsigned short* ksrc = kn + (size_t)(b * 16 + hk) * T_ * 128;
  const unsigned short* tsrc = Tg + (size_t)((b * 32 + h) * 64) * 4096;
  const unsigned short* knsrc = knT + (size_t)(b * 16 + hk) * NCH * 8192;
  const float* gsrc = gjc + (size_t)(b * 32 + h) * 4096;
  const float* bsrc = betab + ((size_t)b * HV_ + h) * T_;

  const int rr = tid >> 4, cc8 = (tid & 15) * 8;  // kl slots

  // pipeline registers (chunk j+1)
  u16x8 krg[4];
  u16x4 vld[4];
  float g_r = 0.f, b_r = 0.f;

  // ---- prologue: load + write chunk 0 (kl, gj, bet) ----
  #pragma unroll
  for (int p = 0; p < 4; ++p) {
    int r = p * 16 + rr;
    krg[p] = *(const u16x8*)(ksrc + (size_t)r * 128 + cc8);
  }
  if (tid < 64) { g_r = gsrc[tid]; b_r = bsrc[tid]; }
  #pragma unroll
  for (int p = 0; p < 4; ++p) {
    int ts = cvl - 3 + p;
    vld[p] = (ts >= 0) ? *(const u16x4*)(mv + (size_t)(b * T_ + ts) * 4096 + h * 128 + u0 + c4)
                       : (u16x4){0, 0, 0, 0};
  }
  #pragma unroll
  for (int p = 0; p < 4; ++p) {
    int r = p * 16 + rr;
    *(u16x8*)&kl[r][cc8] = krg[p];
  }
  if (tid < 64) { gj[tid] = g_r; bet[tid] = b_r; }
  __syncthreads();   // chunk-0 data + ST zero visible

  for (int j = 0; j < NCH; ++j) {
    const int t0 = j * CHK;
    short8 kr[2][2], qf[4], tf[2];
    #pragma unroll
    for (int t2 = 0; t2 < 2; ++t2) {
      int a0 = wv * 32 + t2 * 16;
      #pragma unroll
      for (int ks = 0; ks < 2; ++ks)
        kr[t2][ks] = *(const short8*)(knsrc + (size_t)j * 8192 + (a0 + fr) * 64 + ks * 32 + kg * 8);
    }
    #pragma unroll
    for (int ks = 0; ks < 4; ++ks)
      qf[ks] = *(const short8*)(qsrc + (size_t)(t0 + s0 + fr) * 128 + ks * 32 + kg * 8);
    #pragma unroll
    for (int ks = 0; ks < 2; ++ks)
      tf[ks] = *(const short8*)(tsrc + (size_t)j * 4096 + (s0 + fr) * 64 + ks * 32 + kg * 8);
    // prefetch chunk j+1 kl tiles into regs (T14 issue-early)
    if (j + 1 < NCH) {
      const int t1 = t0 + CHK;
      #pragma unroll
      for (int p = 0; p < 4; ++p) {
        int r = p * 16 + rr;
        krg[p] = *(const u16x8*)(ksrc + (size_t)(t1 + r) * 128 + cc8);
      }
      if (tid < 64) { g_r = gsrc[(j + 1) * 64 + tid]; b_r = bsrc[t1 + tid]; }
    }
    // top compute (chunk j): eg/edec/beg, conv from vld regs, SbT
    if (tid < 64) {
      float gl = gj[63];
      float e = __expf(gj[tid]);
      eg[tid] = e;
      edec[tid] = __expf(gl - gj[tid]);
      beg[tid] = bet[tid] * e;
    }
    {
      float a4[4] = {0.f, 0.f, 0.f, 0.f};
      #pragma unroll
      for (int p = 0; p < 4; ++p)
        #pragma unroll
        for (int i = 0; i < 4; ++i) a4[i] += bf2f(vld[p][i]) * ((const float*)&wv4[i])[p];
      float be = bet[cvl];
      #pragma unroll
      for (int i = 0; i < 4; ++i) {
        float x = a4[i];
        x = x / (1.f + __expf(-x)) * be;
        vbT[c4 + i][cvl] = f2bf(x);
      }
    }
    // prefetch conv-v for chunk j+1
    if (j + 1 < NCH) {
      #pragma unroll
      for (int p = 0; p < 4; ++p) {
        int ts = t0 + CHK + cvl - 3 + p;
        vld[p] = *(const u16x4*)(mv + (size_t)(b * T_ + ts) * 4096 + h * 128 + u0 + c4);
      }
    }
    // SbT = bf16(S^T)
    {
      int u = tid >> 4, a8 = (tid & 15) * 8;
      u16x8 o;
      #pragma unroll
      for (int e = 0; e < 8; ++e) o[e] = f2bf(ST[u][a8 + e]);
      *(u16x8*)&SbT[u][a8] = o;
    }
    __syncthreads();   // barrier2: vbT/SbT/eg/edec/beg ready

    // MM0: Gram q@k^T -> intra (masked, decayed)  [A = qf regs, B = kl LDS]
    {
      f32x4 ag[4];
      #pragma unroll
      for (int mt = 0; mt < 4; ++mt) ag[mt] = (f32x4){0.f, 0.f, 0.f, 0.f};
      #pragma unroll
      for (int ks = 0; ks < 4; ++ks) {
        #pragma unroll
        for (int mt = 0; mt < 4; ++mt) {
          short8 bfv = *(const short8*)&kl[mt * 16 + fr][ks * 32 + kg * 8];
          ag[mt] = __builtin_amdgcn_mfma_f32_16x16x32_bf16(qf[ks], bfv, ag[mt], 0, 0, 0);
        }
      }
      #pragma unroll
      for (int mt = 0; mt < 4; ++mt)
        #pragma unroll
        for (int e = 0; e < 4; ++e) {
          int l = s0 + kg * 4 + e, m = mt * 16 + fr;
          float v = (l >= m) ? (ag[mt][e] * __expf(gj[l] - gj[m])) : 0.f;
          intr[l][m] = f2bf(v);
        }
    }
    // MM1: KS = k@S ; vmr = vb - beg*KS (in place over vbT)
    {
      f32x4 a1 = (f32x4){0.f, 0.f, 0.f, 0.f};
      #pragma unroll
      for (int ks = 0; ks < 4; ++ks) {
        short8 af = *(const short8*)&kl[s0 + fr][ks * 32 + kg * 8];
        short8 bfv = *(const short8*)&SbT[fr][ks * 32 + kg * 8];
        a1 = __builtin_amdgcn_mfma_f32_16x16x32_bf16(af, bfv, a1, 0, 0, 0);
      }
      #pragma unroll
      for (int e = 0; e < 4; ++e) {
        int l = s0 + kg * 4 + e;
        float vm = bf2f(vbT[fr][l]) - beg[l] * a1[e];
        vbT[fr][l] = f2bf(vm);
      }
    }
    __syncthreads();   // barrier3
    // MM2: v_new = T @ vmr ; also vndT = v_new * edec  [A = tf regs]
    {
      f32x4 a2 = (f32x4){0.f, 0.f, 0.f, 0.f};
      #pragma unroll
      for (int ks = 0; ks < 2; ++ks) {
        short8 bfv = *(const short8*)&vbT[fr][ks * 32 + kg * 8];
        a2 = __builtin_amdgcn_mfma_f32_16x16x32_bf16(tf[ks], bfv, a2, 0, 0, 0);
      }
      #pragma unroll
      for (int e = 0; e < 4; ++e) {
        int l = s0 + kg * 4 + e;
        vnT[fr][l]  = f2bf(a2[e]);
        vndT[fr][l] = f2bf(a2[e] * edec[l]);
      }
    }
    __syncthreads();   // barrier4
    // MM4: intra@v_new ; MM5: q@S ; out
    {
      f32x4 ai = (f32x4){0.f, 0.f, 0.f, 0.f};
      f32x4 aq = (f32x4){0.f, 0.f, 0.f, 0.f};
      #pragma unroll
      for (int ks = 0; ks < 2; ++ks) {
        short8 af = *(const short8*)&intr[s0 + fr][ks * 32 + kg * 8];
        short8 bfv = *(const short8*)&vnT[fr][ks * 32 + kg * 8];
        ai = __builtin_amdgcn_mfma_f32_16x16x32_bf16(af, bfv, ai, 0, 0, 0);
      }
      #pragma unroll
      for (int ks = 0; ks < 4; ++ks) {
        short8 bfv = *(const short8*)&SbT[fr][ks * 32 + kg * 8];
        aq = __builtin_amdgcn_mfma_f32_16x16x32_bf16(qf[ks], bfv, aq, 0, 0, 0);
      }
      #pragma unroll
      for (int e = 0; e < 4; ++e) {
        int l = s0 + kg * 4 + e;
        float o = eg[l] * aq[e] + ai[e];
        xout[((size_t)(b * T_ + t0 + l) * HV_ + h) * UV_ + u0 + fr] = f2bf(o);
      }
    }
    // MM6 (MFMA): S^T = eg[63]*S^T + (v_new*edec) @ k^T  [A=vndT (LDS), B=kr (regs)]
    {
      float egl = eg[63];
      #pragma unroll
      for (int t2 = 0; t2 < 2; ++t2) {
        int a0 = wv * 32 + t2 * 16;
        f32x4 cf;
        #pragma unroll
        for (int e = 0; e < 4; ++e) cf[e] = ST[kg * 4 + e][a0 + fr] * egl;
        #pragma unroll
        for (int ks = 0; ks < 2; ++ks) {
          short8 af = *(const short8*)&vndT[fr][ks * 32 + kg * 8];
          cf = __builtin_amdgcn_mfma_f32_16x16x32_bf16(af, kr[t2][ks], cf, 0, 0, 0);
        }
        #pragma unroll
        for (int e = 0; e < 4; ++e) ST[kg * 4 + e][a0 + fr] = cf[e];
      }
    }
    __syncthreads();   // end-of-chunk: all reads of kl/gj/bet done
    // T14 write-late: dump chunk j+1 kl regs into LDS
    if (j + 1 < NCH) {
      #pragma unroll
      for (int p = 0; p < 4; ++p) {
        int r = p * 16 + rr;
        *(u16x8*)&kl[r][cc8] = krg[p];
      }
      if (tid < 64) { gj[tid] = g_r; bet[tid] = b_r; }
    }
    __syncthreads();   // barrier1': chunk j+1 data visible
  }
}

// ---------------- x * silu(z) -> RMSNorm -> bf16 ----------------
__global__ __launch_bounds__(256) void k_gate_norm(const unsigned short* __restrict__ x,
                                                   const unsigned short* __restrict__ z,
                                                   const float* __restrict__ nw,
                                                   unsigned short* __restrict__ out) {
  const int row = blockIdx.x * 4 + (threadIdx.x >> 6);
  const int lane = threadIdx.x & 63;
  const unsigned short* xp = x + (size_t)row * UV_;
  const unsigned short* zp = z + (size_t)row * UV_;
  float x0 = bf2f(xp[lane]), x1 = bf2f(xp[lane + 64]);
  float z0 = bf2f(zp[lane]), z1 = bf2f(zp[lane + 64]);
  float g0 = x0 * (z0 / (1.f + __expf(-z0)));
  float g1 = x1 * (z1 / (1.f + __expf(-z1)));
  float s = g0 * g0 + g1 * g1;
  #pragma unroll
  for (int off = 32; off > 0; off >>= 1) s += __shfl_xor(s, off);
  float r = rsqrtf(s * (1.f / UV_) + 1e-6f);
  out[(size_t)row * UV_ + lane]      = f2bf(nw[lane] * g0 * r);
  out[(size_t)row * UV_ + lane + 64] = f2bf(nw[lane + 64] * g1 * r);
}

// ---------------- launcher ----------------
extern "C" void kernel_launch(void* const* d_in, const int* in_sizes, int n_in,
                              void* d_out, int out_size, void* d_ws, size_t ws_size,
                              hipStream_t stream) {
  (void)in_sizes; (void)n_in; (void)out_size; (void)ws_size;
  const float* hidden  = (const float*)d_in[0];
  const float* W_qkv   = (const float*)d_in[1];
  const float* W_z     = (const float*)d_in[2];
  const float* W_b     = (const float*)d_in[3];
  const float* W_a     = (const float*)d_in[4];
  const float* conv_w  = (const float*)d_in[5];
  const float* dt_bias = (const float*)d_in[6];
  const float* A_log   = (const float*)d_in[7];
  const float* norm_w  = (const float*)d_in[8];
  const float* W_out   = (const float*)d_in[9];
  float* out = (float*)d_out;

  // workspace layout — NOTE: [256,288) MiB is NEVER touched (crash zone, r1/r4/r7/r14).
  //  [  0, 32) wqkvT (->G1)          then Tg   (prep -> scan)
  //  [ 32, 96) mqk  (G1 -> k_qkv)    then xcore (scan -> gate_norm)
  //  [ 96,160) mv   (G1 -> scan)     then normed (gate_norm -> Gout)
  //  [160,192) hidb (beta_g -> mqk/mv GEMMs), then qn (k_qkv -> scan), then zb [160,224)
  //  [192,224) knT  (prep -> scan)
  //  [224,256) kn   (k_qkv -> scan)  then wzT [224,240) + woutT [240,256)
  //  [288,289) betab  [289,290) gbuf  [290,291) gjc   (proven slots)
  const size_t MB = 1048576ull;
  char* w = (char*)d_ws;
  unsigned short* wqkvT = (unsigned short*)(w);
  unsigned short* Tg    = (unsigned short*)(w);
  unsigned short* mqk   = (unsigned short*)(w + 32 * MB);
  unsigned short* xcore = (unsigned short*)(w + 32 * MB);
  unsigned short* mv    = (unsigned short*)(w + 96 * MB);
  unsigned short* normed= (unsigned short*)(w + 96 * MB);
  unsigned short* hidb  = (unsigned short*)(w + 160 * MB);
  unsigned short* qn    = (unsigned short*)(w + 160 * MB);
  unsigned short* zb    = (unsigned short*)(w + 160 * MB);
  unsigned short* knT   = (unsigned short*)(w + 192 * MB);
  unsigned short* kn    = (unsigned short*)(w + 224 * MB);
  unsigned short* wzT   = (unsigned short*)(w + 224 * MB);
  unsigned short* woutT = (unsigned short*)(w + 240 * MB);
  float*          betab = (float*)(w + 288 * MB);
  float*          gbuf  = (float*)(w + 289 * MB);
  float*          gjc   = (float*)(w + 290 * MB);

  // 1. beta/g + bf16 hidden (r18-proven coalesced form)
  k_beta_g<<<dim3(B_ * T_ / 8), 256, 0, stream>>>(hidden, W_b, W_a, dt_bias, A_log, betab, gbuf, hidb);
  // 2. W_qkv^T
  k_transpose<<<dim3(D_ / 32, CD_ / 32), dim3(32, 8), 0, stream>>>(W_qkv, wqkvT, D_, CD_);
  // 3. mqk | mv = hidb @ W_qkv halves (full gload, BK=64)  — hidb dead after
  k_gemm<true, unsigned short><<<dim3(64 * 16), 256, 0, stream>>>(hidb, wqkvT, mqk, 4096, 2048);
  k_gemm<true, unsigned short><<<dim3(64 * 16), 256, 0, stream>>>(hidb, wqkvT + (size_t)4096 * 2048, mv, 4096, 2048);
  // 4. q/k conv+silu+l2norm (qn overwrites dead hidb region)
  k_qkv<<<dim3(B_ * T_), 256, 0, stream>>>(mqk, conv_w, qn, kn);
  // 5. prep: T matrices + gj cumsum + knT
  k_prep<<<dim3(B_ * HV_ * NCH), 256, 0, stream>>>(kn, gbuf, betab, Tg, knT, gjc);
  // 6. scan (XCD-grouped decode + pipelined staging + reg-direct q/T)
  k_scan<<<dim3(B_ * HV_ * 8), 256, 0, stream>>>(qn, kn, mv, Tg, knT, gjc, betab, conv_w, xcore);
  // 7. z path (f32-A GEMM reads d_in hidden directly; into regions freed by scan)
  k_transpose<<<dim3(D_ / 32, VD_ / 32), dim3(32, 8), 0, stream>>>(W_z, wzT, D_, VD_);
  k_gemm<false, unsigned short><<<dim3(64 * 16), 256, 0, stream>>>(hidden, wzT, zb, 4096, 2048);
  k_transpose<<<dim3(VD_ / 32, D_ / 32), dim3(32, 8), 0, stream>>>(W_out, woutT, VD_, D_);
  // 8. gate + RMSNorm
  k_gate_norm<<<dim3(B_ * T_ * HV_ / 4), 256, 0, stream>>>(xcore, zb, norm_w, normed);
  // 9. out = normed @ W_out (full gload)
  k_gemm<true, float><<<dim3(64 * 8), 256, 0, stream>>>(normed, woutT, out, 2048, 4096);
}